// Round 3
// baseline (408.618 us; speedup 1.0000x reference)
//
#include <hip/hip_runtime.h>

typedef short short8 __attribute__((ext_vector_type(8)));
typedef float floatx4 __attribute__((ext_vector_type(4)));
typedef unsigned int uint;
typedef unsigned short ushort;

#define CH 512
#define NN 2048
#define DD 128
#define RSCALE 0.08838834764831845f  // 1/sqrt(128)

__device__ __forceinline__ float bf2f(ushort u) {
    union { uint i; float f; } v; v.i = ((uint)u) << 16; return v.f;
}
__device__ __forceinline__ ushort f2bf(float f) {
    union { float f; uint u; } v; v.f = f;
    uint u = v.u;
    return (ushort)((u + 0x7fffu + ((u >> 16) & 1u)) >> 16);
}

// ---------------------------------------------------------------------------
// K1: projections. Out tile [64 n][64 dstack]; dstack = [wqk rows; wv rows]
// x fp32 [B][C][N] -> Q[b][n][d] (bf16), V[b][n][d] (bf16, + bias)
// ---------------------------------------------------------------------------
__global__ __launch_bounds__(256) void k1_proj(
    const float* __restrict__ x,
    const float* __restrict__ wqk,
    const float* __restrict__ wv,
    const float* __restrict__ bv,
    ushort* __restrict__ Q,
    ushort* __restrict__ V)
{
    const int nt = blockIdx.x;   // 0..31
    const int dt = blockIdx.y;   // 0..3
    const int b  = blockIdx.z;   // 0..7
    const int n0 = nt * 64;
    const int d0 = dt * 64;
    const int t = threadIdx.x;
    const int lane = t & 63;
    const int w = t >> 6;
    const int l15 = lane & 15;
    const int quad = lane >> 4;

    __shared__ __attribute__((aligned(16))) ushort As[64 * 40];
    __shared__ __attribute__((aligned(16))) ushort Bs[64 * 40];

    floatx4 acc[4];
#pragma unroll
    for (int i = 0; i < 4; i++) acc[i] = (floatx4)(0.0f);

    const float* xb = x + b * (CH * NN) + n0;

    for (int c0 = 0; c0 < CH; c0 += 32) {
        // stage A: x^T tile [64 n][32 c], fp32 -> bf16
        {
            int nrow = t & 63, g = t >> 6;
            short8 v;
#pragma unroll
            for (int i = 0; i < 8; i++)
                v[i] = (short)f2bf(xb[(c0 + g * 8 + i) * NN + nrow]);
            *(short8*)&As[nrow * 40 + g * 8] = v;
        }
        // stage B: stacked weights [64 drow][32 c]
#pragma unroll
        for (int rep = 0; rep < 4; rep++) {
            int idx = rep * 256 + t;
            int row = idx >> 4, cp = idx & 15;
            int gr = d0 + row;
            const float* wf = (gr < 128) ? (wqk + gr * CH) : (wv + (gr - 128) * CH);
            uint pack = (uint)f2bf(wf[c0 + cp * 2]) | ((uint)f2bf(wf[c0 + cp * 2 + 1]) << 16);
            *(uint*)&Bs[row * 40 + cp * 2] = pack;
        }
        __syncthreads();
        short8 a = *(short8*)&As[(w * 16 + l15) * 40 + quad * 8];
#pragma unroll
        for (int ct = 0; ct < 4; ct++) {
            short8 bf = *(short8*)&Bs[(ct * 16 + l15) * 40 + quad * 8];
            acc[ct] = __builtin_amdgcn_mfma_f32_16x16x32_bf16(a, bf, acc[ct], 0, 0, 0);
        }
        __syncthreads();
    }
#pragma unroll
    for (int ct = 0; ct < 4; ct++) {
        int ds_ = d0 + ct * 16 + l15;
#pragma unroll
        for (int r = 0; r < 4; r++) {
            int n = n0 + w * 16 + quad * 4 + r;
            float val = acc[ct][r];
            if (ds_ < 128) {
                Q[b * (NN * DD) + n * DD + ds_] = f2bf(val);
            } else {
                int dv = ds_ - 128;
                V[b * (NN * DD) + n * DD + dv] = f2bf(val + bv[dv]);
            }
        }
    }
}

// ---------------------------------------------------------------------------
// K2: l_n = sum_m exp(S[n,m]/sqrt(D)); rescales V in place: V <- V / l_n
// ---------------------------------------------------------------------------
__global__ __launch_bounds__(256) void k2_norm(
    const ushort* __restrict__ Q,  // [B][N][D] bf16
    ushort* __restrict__ V)        // [B][N][D] bf16, in-place rescale
{
    const int ntile = blockIdx.x;  // 0..31
    const int b = blockIdx.y;
    const int n0 = ntile * 64;
    const int t = threadIdx.x;
    const int lane = t & 63, w = t >> 6, l15 = lane & 15, quad = lane >> 4;

    __shared__ __attribute__((aligned(16))) ushort Qs[64 * 136];
    __shared__ __attribute__((aligned(16))) ushort Qm[64 * 136];

    const ushort* Qb = Q + b * (NN * DD);

#pragma unroll
    for (int rep = 0; rep < 16; rep++) {
        int idx = rep * 256 + t;
        int row = idx >> 6, dp = idx & 63;
        *(uint*)&Qs[row * 136 + dp * 2] = *(const uint*)&Qb[(n0 + row) * DD + dp * 2];
    }
    __syncthreads();

    short8 afr[4];
#pragma unroll
    for (int kd = 0; kd < 4; kd++)
        afr[kd] = *(short8*)&Qs[(w * 16 + l15) * 136 + kd * 32 + quad * 8];

    float sums[4] = {0.f, 0.f, 0.f, 0.f};

    for (int m0 = 0; m0 < NN; m0 += 64) {
#pragma unroll
        for (int rep = 0; rep < 16; rep++) {
            int idx = rep * 256 + t;
            int row = idx >> 6, dp = idx & 63;
            *(uint*)&Qm[row * 136 + dp * 2] = *(const uint*)&Qb[(m0 + row) * DD + dp * 2];
        }
        __syncthreads();
#pragma unroll
        for (int ct = 0; ct < 4; ct++) {
            floatx4 s = (floatx4)(0.0f);
#pragma unroll
            for (int kd = 0; kd < 4; kd++) {
                short8 bf = *(short8*)&Qm[(ct * 16 + l15) * 136 + kd * 32 + quad * 8];
                s = __builtin_amdgcn_mfma_f32_16x16x32_bf16(afr[kd], bf, s, 0, 0, 0);
            }
#pragma unroll
            for (int r = 0; r < 4; r++)
                sums[r] += __expf(s[r] * RSCALE);
        }
        __syncthreads();
    }

#pragma unroll
    for (int r = 0; r < 4; r++) {
        float s = sums[r];
        s += __shfl_xor(s, 1);
        s += __shfl_xor(s, 2);
        s += __shfl_xor(s, 4);
        s += __shfl_xor(s, 8);
        sums[r] = s;
    }

    ushort* Vb = V + b * (NN * DD);
#pragma unroll
    for (int r = 0; r < 4; r++) {
        int n = n0 + w * 16 + quad * 4 + r;
        float inv = 1.0f / sums[r];
        short8 vv = *(short8*)&Vb[n * DD + l15 * 8];
        short8 o;
#pragma unroll
        for (int i = 0; i < 8; i++)
            o[i] = (short)f2bf(bf2f((ushort)vv[i]) * inv);
        *(short8*)&Vb[n * DD + l15 * 8] = o;
    }
}

// ---------------------------------------------------------------------------
// K3: out[b][d][m] = sum_n V'[n][d] * exp(S[m][n]/sqrt(D))   (S symmetric)
// out is fp32 [B][D][N]
// ---------------------------------------------------------------------------
__global__ __launch_bounds__(256) void k3_attn(
    const ushort* __restrict__ Q,   // [B][N][D] bf16
    const ushort* __restrict__ Vp,  // [B][N][D] bf16 (V')
    float* __restrict__ out)        // [B][D][N] fp32
{
    const int mtile = blockIdx.x;  // 0..31
    const int b = blockIdx.y;
    const int m0 = mtile * 64;
    const int t = threadIdx.x;
    const int lane = t & 63, w = t >> 6, l15 = lane & 15, quad = lane >> 4;

    __shared__ __attribute__((aligned(16))) ushort Qs[64 * 136];  // block m-rows
    __shared__ __attribute__((aligned(16))) ushort Qn[32 * 136];  // chunk n-rows
    __shared__ __attribute__((aligned(16))) ushort Vs[128 * 40];  // V'^T [d][n]
    __shared__ __attribute__((aligned(16))) ushort Ps[64 * 40];   // P [m][n]

    const ushort* Qb = Q + b * (NN * DD);
    const ushort* Vpb = Vp + b * (NN * DD);

#pragma unroll
    for (int rep = 0; rep < 16; rep++) {
        int idx = rep * 256 + t;
        int row = idx >> 6, dp = idx & 63;
        *(uint*)&Qs[row * 136 + dp * 2] = *(const uint*)&Qb[(m0 + row) * DD + dp * 2];
    }
    __syncthreads();

    short8 afr[4];
#pragma unroll
    for (int kd = 0; kd < 4; kd++)
        afr[kd] = *(short8*)&Qs[(w * 16 + l15) * 136 + kd * 32 + quad * 8];

    floatx4 acc[2][4];
#pragma unroll
    for (int s = 0; s < 2; s++)
#pragma unroll
        for (int mt = 0; mt < 4; mt++) acc[s][mt] = (floatx4)(0.0f);

    for (int n0c = 0; n0c < NN; n0c += 32) {
#pragma unroll
        for (int rep = 0; rep < 8; rep++) {
            int idx = rep * 256 + t;
            int row = idx >> 6, dp = idx & 63;
            *(uint*)&Qn[row * 136 + dp * 2] = *(const uint*)&Qb[(n0c + row) * DD + dp * 2];
        }
#pragma unroll
        for (int rep = 0; rep < 8; rep++) {
            int idx = rep * 256 + t;
            int np = idx >> 7, d = idx & 127;
            uint v0 = Vpb[(n0c + np * 2) * DD + d];
            uint v1 = Vpb[(n0c + np * 2 + 1) * DD + d];
            *(uint*)&Vs[d * 40 + np * 2] = v0 | (v1 << 16);
        }
        __syncthreads();

        // S stage: wave w computes m-rows [w*16, w*16+16), n-cols 0..31
#pragma unroll
        for (int nt2 = 0; nt2 < 2; nt2++) {
            floatx4 s = (floatx4)(0.0f);
#pragma unroll
            for (int kd = 0; kd < 4; kd++) {
                short8 bf = *(short8*)&Qn[(nt2 * 16 + l15) * 136 + kd * 32 + quad * 8];
                s = __builtin_amdgcn_mfma_f32_16x16x32_bf16(afr[kd], bf, s, 0, 0, 0);
            }
#pragma unroll
            for (int r = 0; r < 4; r++) {
                float p = __expf(s[r] * RSCALE);
                Ps[(w * 16 + quad * 4 + r) * 40 + nt2 * 16 + l15] = f2bf(p);
            }
        }
        __syncthreads();

        // PV stage: wave w handles d-band [w*32, w*32+32)
        short8 pb[4];
#pragma unroll
        for (int mt = 0; mt < 4; mt++)
            pb[mt] = *(short8*)&Ps[(mt * 16 + l15) * 40 + quad * 8];
#pragma unroll
        for (int sub = 0; sub < 2; sub++) {
            short8 va = *(short8*)&Vs[(w * 32 + sub * 16 + l15) * 40 + quad * 8];
#pragma unroll
            for (int mt = 0; mt < 4; mt++)
                acc[sub][mt] = __builtin_amdgcn_mfma_f32_16x16x32_bf16(va, pb[mt], acc[sub][mt], 0, 0, 0);
        }
        __syncthreads();
    }

    float* ob = out + b * (DD * NN);
#pragma unroll
    for (int sub = 0; sub < 2; sub++)
#pragma unroll
        for (int mt = 0; mt < 4; mt++)
#pragma unroll
            for (int r = 0; r < 4; r++) {
                int d = w * 32 + sub * 16 + quad * 4 + r;
                int m = m0 + mt * 16 + l15;
                ob[d * NN + m] = acc[sub][mt][r];
            }
}

extern "C" void kernel_launch(void* const* d_in, const int* in_sizes, int n_in,
                              void* d_out, int out_size, void* d_ws, size_t ws_size,
                              hipStream_t stream) {
    const float* x   = (const float*)d_in[0];
    const float* wqk = (const float*)d_in[1];
    const float* wv  = (const float*)d_in[2];
    const float* bv  = (const float*)d_in[3];
    float* out = (float*)d_out;

    // workspace: Q bf16 (4 MiB) | V bf16 (4 MiB)
    ushort* Q = (ushort*)d_ws;
    ushort* V = (ushort*)((char*)d_ws + 4194304);

    dim3 g1(32, 4, 8);
    k1_proj<<<g1, 256, 0, stream>>>(x, wqk, wv, bv, Q, V);
    dim3 g2(32, 8);
    k2_norm<<<g2, 256, 0, stream>>>(Q, V);
    dim3 g3(32, 8);
    k3_attn<<<g3, 256, 0, stream>>>(Q, V, out);
}

// Round 4
// 285.436 us; speedup vs baseline: 1.4316x; 1.4316x over previous
//
#include <hip/hip_runtime.h>

typedef short short4v __attribute__((ext_vector_type(4)));
typedef short short8 __attribute__((ext_vector_type(8)));
typedef float floatx4 __attribute__((ext_vector_type(4)));
typedef unsigned int uint;
typedef unsigned short ushort;

#define CH 512
#define NN 2048
#define DD 128
#define RSCALE 0.08838834764831845f  // 1/sqrt(128)

__device__ __forceinline__ float bf2f(ushort u) {
    union { uint i; float f; } v; v.i = ((uint)u) << 16; return v.f;
}
__device__ __forceinline__ ushort f2bf(float f) {
    union { float f; uint u; } v; v.f = f;
    uint u = v.u;
    return (ushort)((u + 0x7fffu + ((u >> 16) & 1u)) >> 16);
}

// ---------------------------------------------------------------------------
// K1: projections, merged-d. Block = [32 n][256 dstack]; grid (64 nt, 8 b).
// x fp32 read ONCE (128 MB total). Q[b][n][d] bf16, V[b][n][d] bf16 (+bias).
// ---------------------------------------------------------------------------
__global__ __launch_bounds__(256) void k1_proj(
    const float* __restrict__ x,
    const float* __restrict__ wqk,
    const float* __restrict__ wv,
    const float* __restrict__ bv,
    ushort* __restrict__ Q,
    ushort* __restrict__ V)
{
    const int nt = blockIdx.x;   // 0..63
    const int b  = blockIdx.y;   // 0..7
    const int n0 = nt * 32;
    const int t = threadIdx.x;
    const int lane = t & 63, w = t >> 6, l15 = lane & 15, quad = lane >> 4;

    __shared__ __attribute__((aligned(16))) ushort As[32 * 40];   // x^T [n][c]
    __shared__ __attribute__((aligned(16))) ushort Bs[256 * 40];  // w   [dstack][c]

    floatx4 acc[2][4];
#pragma unroll
    for (int i = 0; i < 2; i++)
#pragma unroll
        for (int j = 0; j < 4; j++) acc[i][j] = (floatx4)(0.0f);

    const float* xb = x + b * (CH * NN) + n0;

    for (int c0 = 0; c0 < CH; c0 += 32) {
        // stage A: [32 n][32 c], n fastest across lanes (coalesced)
        {
            int n = t & 31, g = t >> 5;  // 8 c-groups of 4
            short4v v;
#pragma unroll
            for (int i = 0; i < 4; i++)
                v[i] = (short)f2bf(xb[(c0 + g * 4 + i) * NN + n]);
            *(short4v*)&As[n * 40 + g * 4] = v;
        }
        // stage B: [256 dstack][32 c]
#pragma unroll
        for (int rep = 0; rep < 16; rep++) {
            int idx = rep * 256 + t;
            int row = idx >> 4, cp = idx & 15;
            const float* wf = (row < 128) ? (wqk + row * CH) : (wv + (row - 128) * CH);
            uint pack = (uint)f2bf(wf[c0 + cp * 2]) | ((uint)f2bf(wf[c0 + cp * 2 + 1]) << 16);
            *(uint*)&Bs[row * 40 + cp * 2] = pack;
        }
        __syncthreads();
        short8 a0 = *(short8*)&As[(l15) * 40 + quad * 8];
        short8 a1 = *(short8*)&As[(16 + l15) * 40 + quad * 8];
#pragma unroll
        for (int dt2 = 0; dt2 < 4; dt2++) {
            short8 bf = *(short8*)&Bs[(w * 64 + dt2 * 16 + l15) * 40 + quad * 8];
            acc[0][dt2] = __builtin_amdgcn_mfma_f32_16x16x32_bf16(a0, bf, acc[0][dt2], 0, 0, 0);
            acc[1][dt2] = __builtin_amdgcn_mfma_f32_16x16x32_bf16(a1, bf, acc[1][dt2], 0, 0, 0);
        }
        __syncthreads();
    }
#pragma unroll
    for (int ns = 0; ns < 2; ns++)
#pragma unroll
        for (int dt2 = 0; dt2 < 4; dt2++) {
            int ds_ = w * 64 + dt2 * 16 + l15;
#pragma unroll
            for (int r = 0; r < 4; r++) {
                int n = n0 + ns * 16 + quad * 4 + r;
                float val = acc[ns][dt2][r];
                if (ds_ < 128) {
                    Q[b * (NN * DD) + n * DD + ds_] = f2bf(val);
                } else {
                    int dv = ds_ - 128;
                    V[b * (NN * DD) + n * DD + dv] = f2bf(val + bv[dv]);
                }
            }
        }
}

// ---------------------------------------------------------------------------
// K2b (big-ws): block owns 32 n-rows; streams m in 64-chunks.
// Computes P = exp(S/sqrt(D)), stores Pg[b][m][n] (by symmetry) via LDS
// transpose + coalesced rows, and accumulates l_n -> linv[b][n] = 1/l_n.
// ---------------------------------------------------------------------------
__global__ __launch_bounds__(256) void k2_sum_p(
    const ushort* __restrict__ Q,   // [B][N][D] bf16
    ushort* __restrict__ Pg,        // [B][N][N] bf16, row = m, col = n
    float* __restrict__ linv)       // [B][N]
{
    const int ntile = blockIdx.x;  // 0..63
    const int b = blockIdx.y;
    const int n0 = ntile * 32;
    const int t = threadIdx.x;
    const int lane = t & 63, w = t >> 6, l15 = lane & 15, quad = lane >> 4;

    __shared__ __attribute__((aligned(16))) ushort Qs[32 * 136];
    __shared__ __attribute__((aligned(16))) ushort Qm[64 * 136];
    __shared__ __attribute__((aligned(16))) ushort Pt[2][64 * 40];  // [m local][n local]
    __shared__ float red[2][32];

    const ushort* Qb = Q + b * (NN * DD);

#pragma unroll
    for (int rep = 0; rep < 8; rep++) {
        int idx = rep * 256 + t;
        int row = idx >> 6, dp = idx & 63;
        *(uint*)&Qs[row * 136 + dp * 2] = *(const uint*)&Qb[(n0 + row) * DD + dp * 2];
    }
    __syncthreads();

    short8 afr[4];
#pragma unroll
    for (int kd = 0; kd < 4; kd++)
        afr[kd] = *(short8*)&Qs[((w & 1) * 16 + l15) * 136 + kd * 32 + quad * 8];

    const int ctb = (w >> 1) * 2;
    float sums[4] = {0.f, 0.f, 0.f, 0.f};

    int buf = 0;
    for (int m0 = 0; m0 < NN; m0 += 64, buf ^= 1) {
#pragma unroll
        for (int rep = 0; rep < 16; rep++) {
            int idx = rep * 256 + t;
            int row = idx >> 6, dp = idx & 63;
            *(uint*)&Qm[row * 136 + dp * 2] = *(const uint*)&Qb[(m0 + row) * DD + dp * 2];
        }
        __syncthreads();
#pragma unroll
        for (int ct = 0; ct < 2; ct++) {
            int cm = ctb + ct;
            floatx4 s = (floatx4)(0.0f);
#pragma unroll
            for (int kd = 0; kd < 4; kd++) {
                short8 bf = *(short8*)&Qm[(cm * 16 + l15) * 136 + kd * 32 + quad * 8];
                s = __builtin_amdgcn_mfma_f32_16x16x32_bf16(afr[kd], bf, s, 0, 0, 0);
            }
#pragma unroll
            for (int r = 0; r < 4; r++) {
                float p = __expf(s[r] * RSCALE);
                sums[r] += p;
                // m local = cm*16+l15, n local = (w&1)*16 + quad*4 + r
                Pt[buf][(cm * 16 + l15) * 40 + (w & 1) * 16 + quad * 4 + r] = f2bf(p);
            }
        }
        __syncthreads();
        // coop store Pt[buf] -> Pg rows m0..m0+64, cols n0..n0+32 (coalesced)
#pragma unroll
        for (int rep = 0; rep < 4; rep++) {
            int idx = rep * 256 + t;
            int row = idx >> 4, col2 = idx & 15;
            *(uint*)&Pg[(size_t)b * NN * NN + (size_t)(m0 + row) * NN + n0 + col2 * 2] =
                *(uint*)&Pt[buf][row * 40 + col2 * 2];
        }
    }

#pragma unroll
    for (int r = 0; r < 4; r++) {
        float s = sums[r];
        s += __shfl_xor(s, 1);
        s += __shfl_xor(s, 2);
        s += __shfl_xor(s, 4);
        s += __shfl_xor(s, 8);
        sums[r] = s;
    }
    if (l15 == 0) {
#pragma unroll
        for (int r = 0; r < 4; r++)
            red[w >> 1][(w & 1) * 16 + quad * 4 + r] = sums[r];
    }
    __syncthreads();
    if (t < 32)
        linv[b * NN + n0 + t] = 1.0f / (red[0][t] + red[1][t]);
}

// ---------------------------------------------------------------------------
// K2c (big-ws): V'T[b][d][n] = V[b][n][d] * linv[b][n]  (LDS transpose)
// ---------------------------------------------------------------------------
__global__ __launch_bounds__(256) void k2_scale_t(
    const ushort* __restrict__ V,
    const float* __restrict__ linv,
    ushort* __restrict__ VT)
{
    const int nt = blockIdx.x;  // 0..31
    const int b = blockIdx.y;
    const int n0 = nt * 64;
    const int t = threadIdx.x;

    __shared__ __attribute__((aligned(16))) ushort Vt[64 * 132];

    const ushort* Vb = V + b * (NN * DD);
#pragma unroll
    for (int rep = 0; rep < 16; rep++) {
        int idx = rep * 256 + t;
        int row = idx >> 6, dp = idx & 63;
        *(uint*)&Vt[row * 132 + dp * 2] = *(const uint*)&Vb[(n0 + row) * DD + dp * 2];
    }
    __syncthreads();
#pragma unroll
    for (int rep = 0; rep < 16; rep++) {
        int idx = rep * 256 + t;
        int d = idx >> 5, col2 = idx & 31;
        int n = n0 + col2 * 2;
        float l0 = linv[b * NN + n], l1 = linv[b * NN + n + 1];
        float v0 = bf2f(Vt[(col2 * 2) * 132 + d]) * l0;
        float v1 = bf2f(Vt[(col2 * 2 + 1) * 132 + d]) * l1;
        uint pack = (uint)f2bf(v0) | ((uint)f2bf(v1) << 16);
        *(uint*)&VT[(size_t)b * DD * NN + (size_t)d * NN + n] = pack;
    }
}

// ---------------------------------------------------------------------------
// K3b (big-ws): pure GEMM. out[b][d][m] = sum_n VT[d][n] * Pg[m][n].
// Block = [128 d][32 m], n-chunk 64; grid (64, 8) = 512 blocks (2/CU).
// ---------------------------------------------------------------------------
__global__ __launch_bounds__(256) void k3_gemm(
    const ushort* __restrict__ VT,  // [B][D][N] bf16
    const ushort* __restrict__ Pg,  // [B][N][N] bf16 (row m, col n)
    float* __restrict__ out)        // [B][D][N] fp32
{
    const int mt2 = blockIdx.x;  // 0..63
    const int b = blockIdx.y;
    const int m0 = mt2 * 32;
    const int t = threadIdx.x;
    const int lane = t & 63, w = t >> 6, l15 = lane & 15, quad = lane >> 4;

    __shared__ __attribute__((aligned(16))) ushort As2[128 * 72];
    __shared__ __attribute__((aligned(16))) ushort Ps2[32 * 72];

    const ushort* VTb = VT + (size_t)b * DD * NN;
    const ushort* Pb = Pg + (size_t)b * NN * NN;

    floatx4 acc[2][2];
#pragma unroll
    for (int i = 0; i < 2; i++)
#pragma unroll
        for (int j = 0; j < 2; j++) acc[i][j] = (floatx4)(0.0f);

    for (int n0c = 0; n0c < NN; n0c += 64) {
#pragma unroll
        for (int rep = 0; rep < 16; rep++) {
            int idx = rep * 256 + t;
            int row = idx >> 5, col2 = idx & 31;
            *(uint*)&As2[row * 72 + col2 * 2] = *(const uint*)&VTb[(size_t)row * NN + n0c + col2 * 2];
        }
#pragma unroll
        for (int rep = 0; rep < 4; rep++) {
            int idx = rep * 256 + t;
            int row = idx >> 5, col2 = idx & 31;
            *(uint*)&Ps2[row * 72 + col2 * 2] = *(const uint*)&Pb[(size_t)(m0 + row) * NN + n0c + col2 * 2];
        }
        __syncthreads();
#pragma unroll
        for (int kn = 0; kn < 2; kn++) {
            short8 pb0 = *(short8*)&Ps2[(l15) * 72 + kn * 32 + quad * 8];
            short8 pb1 = *(short8*)&Ps2[(16 + l15) * 72 + kn * 32 + quad * 8];
#pragma unroll
            for (int sub = 0; sub < 2; sub++) {
                short8 va = *(short8*)&As2[(w * 32 + sub * 16 + l15) * 72 + kn * 32 + quad * 8];
                acc[sub][0] = __builtin_amdgcn_mfma_f32_16x16x32_bf16(va, pb0, acc[sub][0], 0, 0, 0);
                acc[sub][1] = __builtin_amdgcn_mfma_f32_16x16x32_bf16(va, pb1, acc[sub][1], 0, 0, 0);
            }
        }
        __syncthreads();
    }

    float* ob = out + (size_t)b * DD * NN;
#pragma unroll
    for (int sub = 0; sub < 2; sub++)
#pragma unroll
        for (int mtk = 0; mtk < 2; mtk++)
#pragma unroll
            for (int r = 0; r < 4; r++) {
                int d = w * 32 + sub * 16 + quad * 4 + r;
                int m = m0 + mtk * 16 + l15;
                ob[(size_t)d * NN + m] = acc[sub][mtk][r];
            }
}

// ---------------------------------------------------------------------------
// Fallback path (small ws): round-3 proven kernels (Q,V layouts unchanged)
// ---------------------------------------------------------------------------
__global__ __launch_bounds__(256) void k2_norm(
    const ushort* __restrict__ Q, ushort* __restrict__ V)
{
    const int ntile = blockIdx.x;
    const int b = blockIdx.y;
    const int n0 = ntile * 64;
    const int t = threadIdx.x;
    const int lane = t & 63, w = t >> 6, l15 = lane & 15, quad = lane >> 4;

    __shared__ __attribute__((aligned(16))) ushort Qs[64 * 136];
    __shared__ __attribute__((aligned(16))) ushort Qm[64 * 136];

    const ushort* Qb = Q + b * (NN * DD);

#pragma unroll
    for (int rep = 0; rep < 16; rep++) {
        int idx = rep * 256 + t;
        int row = idx >> 6, dp = idx & 63;
        *(uint*)&Qs[row * 136 + dp * 2] = *(const uint*)&Qb[(n0 + row) * DD + dp * 2];
    }
    __syncthreads();

    short8 afr[4];
#pragma unroll
    for (int kd = 0; kd < 4; kd++)
        afr[kd] = *(short8*)&Qs[(w * 16 + l15) * 136 + kd * 32 + quad * 8];

    float sums[4] = {0.f, 0.f, 0.f, 0.f};

    for (int m0 = 0; m0 < NN; m0 += 64) {
#pragma unroll
        for (int rep = 0; rep < 16; rep++) {
            int idx = rep * 256 + t;
            int row = idx >> 6, dp = idx & 63;
            *(uint*)&Qm[row * 136 + dp * 2] = *(const uint*)&Qb[(m0 + row) * DD + dp * 2];
        }
        __syncthreads();
#pragma unroll
        for (int ct = 0; ct < 4; ct++) {
            floatx4 s = (floatx4)(0.0f);
#pragma unroll
            for (int kd = 0; kd < 4; kd++) {
                short8 bf = *(short8*)&Qm[(ct * 16 + l15) * 136 + kd * 32 + quad * 8];
                s = __builtin_amdgcn_mfma_f32_16x16x32_bf16(afr[kd], bf, s, 0, 0, 0);
            }
#pragma unroll
            for (int r = 0; r < 4; r++)
                sums[r] += __expf(s[r] * RSCALE);
        }
        __syncthreads();
    }

#pragma unroll
    for (int r = 0; r < 4; r++) {
        float s = sums[r];
        s += __shfl_xor(s, 1);
        s += __shfl_xor(s, 2);
        s += __shfl_xor(s, 4);
        s += __shfl_xor(s, 8);
        sums[r] = s;
    }

    ushort* Vb = V + b * (NN * DD);
#pragma unroll
    for (int r = 0; r < 4; r++) {
        int n = n0 + w * 16 + quad * 4 + r;
        float inv = 1.0f / sums[r];
        short8 vv = *(short8*)&Vb[n * DD + l15 * 8];
        short8 o;
#pragma unroll
        for (int i = 0; i < 8; i++)
            o[i] = (short)f2bf(bf2f((ushort)vv[i]) * inv);
        *(short8*)&Vb[n * DD + l15 * 8] = o;
    }
}

__global__ __launch_bounds__(256) void k3_attn(
    const ushort* __restrict__ Q, const ushort* __restrict__ Vp,
    float* __restrict__ out)
{
    const int mtile = blockIdx.x;
    const int b = blockIdx.y;
    const int m0 = mtile * 64;
    const int t = threadIdx.x;
    const int lane = t & 63, w = t >> 6, l15 = lane & 15, quad = lane >> 4;

    __shared__ __attribute__((aligned(16))) ushort Qs[64 * 136];
    __shared__ __attribute__((aligned(16))) ushort Qn[32 * 136];
    __shared__ __attribute__((aligned(16))) ushort Vs[128 * 40];
    __shared__ __attribute__((aligned(16))) ushort Ps[64 * 40];

    const ushort* Qb = Q + b * (NN * DD);
    const ushort* Vpb = Vp + b * (NN * DD);

#pragma unroll
    for (int rep = 0; rep < 16; rep++) {
        int idx = rep * 256 + t;
        int row = idx >> 6, dp = idx & 63;
        *(uint*)&Qs[row * 136 + dp * 2] = *(const uint*)&Qb[(m0 + row) * DD + dp * 2];
    }
    __syncthreads();

    short8 afr[4];
#pragma unroll
    for (int kd = 0; kd < 4; kd++)
        afr[kd] = *(short8*)&Qs[(w * 16 + l15) * 136 + kd * 32 + quad * 8];

    floatx4 acc[2][4];
#pragma unroll
    for (int s = 0; s < 2; s++)
#pragma unroll
        for (int mt = 0; mt < 4; mt++) acc[s][mt] = (floatx4)(0.0f);

    for (int n0c = 0; n0c < NN; n0c += 32) {
#pragma unroll
        for (int rep = 0; rep < 8; rep++) {
            int idx = rep * 256 + t;
            int row = idx >> 6, dp = idx & 63;
            *(uint*)&Qn[row * 136 + dp * 2] = *(const uint*)&Qb[(n0c + row) * DD + dp * 2];
        }
#pragma unroll
        for (int rep = 0; rep < 8; rep++) {
            int idx = rep * 256 + t;
            int np = idx >> 7, d = idx & 127;
            uint v0 = Vpb[(n0c + np * 2) * DD + d];
            uint v1 = Vpb[(n0c + np * 2 + 1) * DD + d];
            *(uint*)&Vs[d * 40 + np * 2] = v0 | (v1 << 16);
        }
        __syncthreads();

#pragma unroll
        for (int nt2 = 0; nt2 < 2; nt2++) {
            floatx4 s = (floatx4)(0.0f);
#pragma unroll
            for (int kd = 0; kd < 4; kd++) {
                short8 bf = *(short8*)&Qn[(nt2 * 16 + l15) * 136 + kd * 32 + quad * 8];
                s = __builtin_amdgcn_mfma_f32_16x16x32_bf16(afr[kd], bf, s, 0, 0, 0);
            }
#pragma unroll
            for (int r = 0; r < 4; r++) {
                float p = __expf(s[r] * RSCALE);
                Ps[(w * 16 + quad * 4 + r) * 40 + nt2 * 16 + l15] = f2bf(p);
            }
        }
        __syncthreads();

        short8 pb[4];
#pragma unroll
        for (int mt = 0; mt < 4; mt++)
            pb[mt] = *(short8*)&Ps[(mt * 16 + l15) * 40 + quad * 8];
#pragma unroll
        for (int sub = 0; sub < 2; sub++) {
            short8 va = *(short8*)&Vs[(w * 32 + sub * 16 + l15) * 40 + quad * 8];
#pragma unroll
            for (int mt = 0; mt < 4; mt++)
                acc[sub][mt] = __builtin_amdgcn_mfma_f32_16x16x32_bf16(va, pb[mt], acc[sub][mt], 0, 0, 0);
        }
        __syncthreads();
    }

    float* ob = out + (size_t)b * DD * NN;
#pragma unroll
    for (int sub = 0; sub < 2; sub++)
#pragma unroll
        for (int mt = 0; mt < 4; mt++)
#pragma unroll
            for (int r = 0; r < 4; r++) {
                int d = w * 32 + sub * 16 + quad * 4 + r;
                int m = m0 + mt * 16 + l15;
                ob[(size_t)d * NN + m] = acc[sub][mt][r];
            }
}

extern "C" void kernel_launch(void* const* d_in, const int* in_sizes, int n_in,
                              void* d_out, int out_size, void* d_ws, size_t ws_size,
                              hipStream_t stream) {
    const float* x   = (const float*)d_in[0];
    const float* wqk = (const float*)d_in[1];
    const float* wv  = (const float*)d_in[2];
    const float* bv  = (const float*)d_in[3];
    float* out = (float*)d_out;

    // ws layout: Q bf16 [0,4MiB) | V bf16 [4,8MiB)
    // big path adds: linv fp32 @8MiB (64KB) | VT bf16 @12MiB (4MiB) | Pg bf16 @16MiB (64MiB)
    ushort* Q = (ushort*)d_ws;
    ushort* V = (ushort*)((char*)d_ws + (4u << 20));

    dim3 g1(64, 8);
    k1_proj<<<g1, 256, 0, stream>>>(x, wqk, wv, bv, Q, V);

    if (ws_size >= (size_t)80 * 1024 * 1024) {
        float*  linv = (float*)((char*)d_ws + (8u << 20));
        ushort* VT   = (ushort*)((char*)d_ws + (12u << 20));
        ushort* Pg   = (ushort*)((char*)d_ws + (16u << 20));
        k2_sum_p<<<dim3(64, 8), 256, 0, stream>>>(Q, Pg, linv);
        k2_scale_t<<<dim3(32, 8), 256, 0, stream>>>(V, linv, VT);
        k3_gemm<<<dim3(64, 8), 256, 0, stream>>>(VT, Pg, out);
    } else {
        k2_norm<<<dim3(32, 8), 256, 0, stream>>>(Q, V);
        k3_attn<<<dim3(32, 8), 256, 0, stream>>>(Q, V, out);
    }
}

// Round 5
// 182.012 us; speedup vs baseline: 2.2450x; 1.5682x over previous
//
#include <hip/hip_runtime.h>

typedef short short4v __attribute__((ext_vector_type(4)));
typedef short short8 __attribute__((ext_vector_type(8)));
typedef float floatx4 __attribute__((ext_vector_type(4)));
typedef unsigned int uint;
typedef unsigned short ushort;

#define CH 512
#define NN 2048
#define DD 128
#define RSCALE 0.08838834764831845f  // 1/sqrt(128)

__device__ __forceinline__ float bf2f(ushort u) {
    union { uint i; float f; } v; v.i = ((uint)u) << 16; return v.f;
}
__device__ __forceinline__ ushort f2bf(float f) {
    union { float f; uint u; } v; v.f = f;
    uint u = v.u;
    return (ushort)((u + 0x7fffu + ((u >> 16) & 1u)) >> 16);
}

// ---------------------------------------------------------------------------
// K0a: zero lsum[8][2048] (ws is re-poisoned to 0xAA before every call)
// ---------------------------------------------------------------------------
__global__ void k0_zero(float* __restrict__ lsum) {
    lsum[blockIdx.x * 256 + threadIdx.x] = 0.0f;
}

// ---------------------------------------------------------------------------
// K0b: pre-convert weights to bf16. Wbf[256][512]: rows 0-127 = wqk, 128-255 = wv
// ---------------------------------------------------------------------------
__global__ __launch_bounds__(256) void k0_wconv(
    const float* __restrict__ wqk, const float* __restrict__ wv,
    ushort* __restrict__ Wbf)
{
    int gid = blockIdx.x * 256 + threadIdx.x;  // 32768 float4 groups
    int base = gid * 4;
    const float* src = (base < 65536) ? (wqk + base) : (wv + base - 65536);
    float4 v = *(const float4*)src;
    short4v o;
    o[0] = (short)f2bf(v.x); o[1] = (short)f2bf(v.y);
    o[2] = (short)f2bf(v.z); o[3] = (short)f2bf(v.w);
    *(short4v*)&Wbf[base] = o;
}

// ---------------------------------------------------------------------------
// K1: projections, merged-d, bf16 weights. Block = [32 n][256 dstack].
// x fp32 read once. Q[b][n][d] bf16, V[b][n][d] bf16 (+bias).
// ---------------------------------------------------------------------------
__global__ __launch_bounds__(256) void k1_proj(
    const float* __restrict__ x,
    const ushort* __restrict__ Wbf,
    const float* __restrict__ bv,
    ushort* __restrict__ Q,
    ushort* __restrict__ V)
{
    const int nt = blockIdx.x;   // 0..63
    const int b  = blockIdx.y;   // 0..7
    const int n0 = nt * 32;
    const int t = threadIdx.x;
    const int lane = t & 63, w = t >> 6, l15 = lane & 15, quad = lane >> 4;

    __shared__ __attribute__((aligned(16))) ushort As[32 * 40];   // x^T [n][c]
    __shared__ __attribute__((aligned(16))) ushort Bs[256 * 40];  // w   [dstack][c]

    floatx4 acc[2][4];
#pragma unroll
    for (int i = 0; i < 2; i++)
#pragma unroll
        for (int j = 0; j < 4; j++) acc[i][j] = (floatx4)(0.0f);

    const float* xb = x + b * (CH * NN) + n0;

    for (int c0 = 0; c0 < CH; c0 += 32) {
        // stage A: [32 n][32 c], fp32 -> bf16
        {
            int n = t & 31, g = t >> 5;
            short4v v;
#pragma unroll
            for (int i = 0; i < 4; i++)
                v[i] = (short)f2bf(xb[(c0 + g * 4 + i) * NN + n]);
            *(short4v*)&As[n * 40 + g * 4] = v;
        }
        // stage B: [256 dstack][32 c] plain bf16 copies
#pragma unroll
        for (int rep = 0; rep < 16; rep++) {
            int idx = rep * 256 + t;
            int row = idx >> 4, cp = idx & 15;
            *(uint*)&Bs[row * 40 + cp * 2] = *(const uint*)&Wbf[row * CH + c0 + cp * 2];
        }
        __syncthreads();
        short8 a0 = *(short8*)&As[(l15) * 40 + quad * 8];
        short8 a1 = *(short8*)&As[(16 + l15) * 40 + quad * 8];
#pragma unroll
        for (int dt2 = 0; dt2 < 4; dt2++) {
            short8 bf = *(short8*)&Bs[(w * 64 + dt2 * 16 + l15) * 40 + quad * 8];
            acc[0][dt2] = __builtin_amdgcn_mfma_f32_16x16x32_bf16(a0, bf, acc[0][dt2], 0, 0, 0);
            acc[1][dt2] = __builtin_amdgcn_mfma_f32_16x16x32_bf16(a1, bf, acc[1][dt2], 0, 0, 0);
        }
        __syncthreads();
    }
#pragma unroll
    for (int ns = 0; ns < 2; ns++)
#pragma unroll
        for (int dt2 = 0; dt2 < 4; dt2++) {
            int ds_ = w * 64 + dt2 * 16 + l15;
#pragma unroll
            for (int r = 0; r < 4; r++) {
                int n = n0 + ns * 16 + quad * 4 + r;
                float val = acc[ns][dt2][r];
                if (ds_ < 128) {
                    Q[b * (NN * DD) + n * DD + ds_] = f2bf(val);
                } else {
                    int dv = ds_ - 128;
                    V[b * (NN * DD) + n * DD + dv] = f2bf(val + bv[dv]);
                }
            }
        }
}

// ---------------------------------------------------------------------------
// K2: Q.Q^T tile GEMM. Block computes 128(i) x 64(j) S-tile, K=128 fully in
// LDS, no mid-loop barriers. Epilogue: P = exp(S/sqrt(D)) -> Pg[b][i][j],
// row-sums -> atomicAdd lsum[b][i].
// ---------------------------------------------------------------------------
__global__ __launch_bounds__(256) void k2_qqt(
    const ushort* __restrict__ Q,   // [B][N][D] bf16
    ushort* __restrict__ Pg,        // [B][N][N] bf16
    float* __restrict__ lsum)       // [B][N]
{
    const int it = blockIdx.x;   // 0..15
    const int jt = blockIdx.y;   // 0..31
    const int b  = blockIdx.z;
    const int i0 = it * 128, j0 = jt * 64;
    const int t = threadIdx.x;
    const int lane = t & 63, w = t >> 6, l15 = lane & 15, quad = lane >> 4;
    const int wi = (w >> 1) * 64, wj = (w & 1) * 32;

    __shared__ __attribute__((aligned(16))) ushort Qi[128 * 136];
    __shared__ __attribute__((aligned(16))) ushort Qj[64 * 136];

    const ushort* Qb = Q + b * (NN * DD);

#pragma unroll
    for (int rep = 0; rep < 8; rep++) {
        int idx = rep * 256 + t;
        int row = idx >> 4, g = idx & 15;
        *(short8*)&Qi[row * 136 + g * 8] = *(const short8*)&Qb[(i0 + row) * DD + g * 8];
    }
#pragma unroll
    for (int rep = 0; rep < 4; rep++) {
        int idx = rep * 256 + t;
        int row = idx >> 4, g = idx & 15;
        *(short8*)&Qj[row * 136 + g * 8] = *(const short8*)&Qb[(j0 + row) * DD + g * 8];
    }
    __syncthreads();

    floatx4 acc[4][2];
#pragma unroll
    for (int i = 0; i < 4; i++)
#pragma unroll
        for (int j = 0; j < 2; j++) acc[i][j] = (floatx4)(0.0f);

#pragma unroll
    for (int kd = 0; kd < 4; kd++) {
        short8 afr[4], bfr[2];
#pragma unroll
        for (int nt = 0; nt < 4; nt++)
            afr[nt] = *(short8*)&Qi[(wi + nt * 16 + l15) * 136 + kd * 32 + quad * 8];
#pragma unroll
        for (int mt = 0; mt < 2; mt++)
            bfr[mt] = *(short8*)&Qj[(wj + mt * 16 + l15) * 136 + kd * 32 + quad * 8];
#pragma unroll
        for (int nt = 0; nt < 4; nt++)
#pragma unroll
            for (int mt = 0; mt < 2; mt++)
                acc[nt][mt] = __builtin_amdgcn_mfma_f32_16x16x32_bf16(afr[nt], bfr[mt], acc[nt][mt], 0, 0, 0);
    }

    ushort* Pb = Pg + (size_t)b * NN * NN;
#pragma unroll
    for (int nt = 0; nt < 4; nt++) {
        float rs[4] = {0.f, 0.f, 0.f, 0.f};
#pragma unroll
        for (int mt = 0; mt < 2; mt++) {
#pragma unroll
            for (int r = 0; r < 4; r++) {
                float p = __expf(acc[nt][mt][r] * RSCALE);
                rs[r] += p;
                Pb[(size_t)(i0 + wi + nt * 16 + quad * 4 + r) * NN + (j0 + wj + mt * 16 + l15)] = f2bf(p);
            }
        }
#pragma unroll
        for (int r = 0; r < 4; r++) {
            float s = rs[r];
            s += __shfl_xor(s, 1);
            s += __shfl_xor(s, 2);
            s += __shfl_xor(s, 4);
            s += __shfl_xor(s, 8);
            if (l15 == 0)
                atomicAdd(&lsum[b * NN + i0 + wi + nt * 16 + quad * 4 + r], s);
        }
    }
}

// ---------------------------------------------------------------------------
// K2c: VT[b][d][n] = V[b][n][d] / lsum[b][n]  (LDS transpose)
// ---------------------------------------------------------------------------
__global__ __launch_bounds__(256) void k2_scale_t(
    const ushort* __restrict__ V,
    const float* __restrict__ lsum,
    ushort* __restrict__ VT)
{
    const int nt = blockIdx.x;  // 0..31
    const int b = blockIdx.y;
    const int n0 = nt * 64;
    const int t = threadIdx.x;

    __shared__ __attribute__((aligned(16))) ushort Vt[64 * 132];

    const ushort* Vb = V + b * (NN * DD);
#pragma unroll
    for (int rep = 0; rep < 16; rep++) {
        int idx = rep * 256 + t;
        int row = idx >> 6, dp = idx & 63;
        *(uint*)&Vt[row * 132 + dp * 2] = *(const uint*)&Vb[(n0 + row) * DD + dp * 2];
    }
    __syncthreads();
#pragma unroll
    for (int rep = 0; rep < 16; rep++) {
        int idx = rep * 256 + t;
        int d = idx >> 5, col2 = idx & 31;
        int n = n0 + col2 * 2;
        float l0 = 1.0f / lsum[b * NN + n], l1 = 1.0f / lsum[b * NN + n + 1];
        float v0 = bf2f(Vt[(col2 * 2) * 132 + d]) * l0;
        float v1 = bf2f(Vt[(col2 * 2 + 1) * 132 + d]) * l1;
        uint pack = (uint)f2bf(v0) | ((uint)f2bf(v1) << 16);
        *(uint*)&VT[(size_t)b * DD * NN + (size_t)d * NN + n] = pack;
    }
}

// ---------------------------------------------------------------------------
// K3: pure GEMM. out[b][d][m] = sum_n VT[d][n] * Pg[m][n].
// ---------------------------------------------------------------------------
__global__ __launch_bounds__(256) void k3_gemm(
    const ushort* __restrict__ VT,  // [B][D][N] bf16
    const ushort* __restrict__ Pg,  // [B][N][N] bf16
    float* __restrict__ out)        // [B][D][N] fp32
{
    const int mt2 = blockIdx.x;  // 0..63
    const int b = blockIdx.y;
    const int m0 = mt2 * 32;
    const int t = threadIdx.x;
    const int lane = t & 63, w = t >> 6, l15 = lane & 15, quad = lane >> 4;

    __shared__ __attribute__((aligned(16))) ushort As2[128 * 72];
    __shared__ __attribute__((aligned(16))) ushort Ps2[32 * 72];

    const ushort* VTb = VT + (size_t)b * DD * NN;
    const ushort* Pb = Pg + (size_t)b * NN * NN;

    floatx4 acc[2][2];
#pragma unroll
    for (int i = 0; i < 2; i++)
#pragma unroll
        for (int j = 0; j < 2; j++) acc[i][j] = (floatx4)(0.0f);

    for (int n0c = 0; n0c < NN; n0c += 64) {
#pragma unroll
        for (int rep = 0; rep < 16; rep++) {
            int idx = rep * 256 + t;
            int row = idx >> 5, col2 = idx & 31;
            *(uint*)&As2[row * 72 + col2 * 2] = *(const uint*)&VTb[(size_t)row * NN + n0c + col2 * 2];
        }
#pragma unroll
        for (int rep = 0; rep < 4; rep++) {
            int idx = rep * 256 + t;
            int row = idx >> 5, col2 = idx & 31;
            *(uint*)&Ps2[row * 72 + col2 * 2] = *(const uint*)&Pb[(size_t)(m0 + row) * NN + n0c + col2 * 2];
        }
        __syncthreads();
#pragma unroll
        for (int kn = 0; kn < 2; kn++) {
            short8 pb0 = *(short8*)&Ps2[(l15) * 72 + kn * 32 + quad * 8];
            short8 pb1 = *(short8*)&Ps2[(16 + l15) * 72 + kn * 32 + quad * 8];
#pragma unroll
            for (int sub = 0; sub < 2; sub++) {
                short8 va = *(short8*)&As2[(w * 32 + sub * 16 + l15) * 72 + kn * 32 + quad * 8];
                acc[sub][0] = __builtin_amdgcn_mfma_f32_16x16x32_bf16(va, pb0, acc[sub][0], 0, 0, 0);
                acc[sub][1] = __builtin_amdgcn_mfma_f32_16x16x32_bf16(va, pb1, acc[sub][1], 0, 0, 0);
            }
        }
        __syncthreads();
    }

    float* ob = out + (size_t)b * DD * NN;
#pragma unroll
    for (int sub = 0; sub < 2; sub++)
#pragma unroll
        for (int mtk = 0; mtk < 2; mtk++)
#pragma unroll
            for (int r = 0; r < 4; r++) {
                int d = w * 32 + sub * 16 + quad * 4 + r;
                int m = m0 + mtk * 16 + l15;
                ob[(size_t)d * NN + m] = acc[sub][mtk][r];
            }
}

// ---------------------------------------------------------------------------
// Fallback path (small ws) — round-3 proven kernels, fp32 weights inline
// ---------------------------------------------------------------------------
__global__ __launch_bounds__(256) void k1_fb(
    const float* __restrict__ x, const float* __restrict__ wqk,
    const float* __restrict__ wv, const float* __restrict__ bv,
    ushort* __restrict__ Q, ushort* __restrict__ V)
{
    const int nt = blockIdx.x;
    const int b  = blockIdx.y;
    const int n0 = nt * 32;
    const int t = threadIdx.x;
    const int lane = t & 63, w = t >> 6, l15 = lane & 15, quad = lane >> 4;

    __shared__ __attribute__((aligned(16))) ushort As[32 * 40];
    __shared__ __attribute__((aligned(16))) ushort Bs[256 * 40];

    floatx4 acc[2][4];
#pragma unroll
    for (int i = 0; i < 2; i++)
#pragma unroll
        for (int j = 0; j < 4; j++) acc[i][j] = (floatx4)(0.0f);

    const float* xb = x + b * (CH * NN) + n0;

    for (int c0 = 0; c0 < CH; c0 += 32) {
        {
            int n = t & 31, g = t >> 5;
            short4v v;
#pragma unroll
            for (int i = 0; i < 4; i++)
                v[i] = (short)f2bf(xb[(c0 + g * 4 + i) * NN + n]);
            *(short4v*)&As[n * 40 + g * 4] = v;
        }
#pragma unroll
        for (int rep = 0; rep < 16; rep++) {
            int idx = rep * 256 + t;
            int row = idx >> 4, cp = idx & 15;
            const float* wf = (row < 128) ? (wqk + row * CH) : (wv + (row - 128) * CH);
            uint pack = (uint)f2bf(wf[c0 + cp * 2]) | ((uint)f2bf(wf[c0 + cp * 2 + 1]) << 16);
            *(uint*)&Bs[row * 40 + cp * 2] = pack;
        }
        __syncthreads();
        short8 a0 = *(short8*)&As[(l15) * 40 + quad * 8];
        short8 a1 = *(short8*)&As[(16 + l15) * 40 + quad * 8];
#pragma unroll
        for (int dt2 = 0; dt2 < 4; dt2++) {
            short8 bf = *(short8*)&Bs[(w * 64 + dt2 * 16 + l15) * 40 + quad * 8];
            acc[0][dt2] = __builtin_amdgcn_mfma_f32_16x16x32_bf16(a0, bf, acc[0][dt2], 0, 0, 0);
            acc[1][dt2] = __builtin_amdgcn_mfma_f32_16x16x32_bf16(a1, bf, acc[1][dt2], 0, 0, 0);
        }
        __syncthreads();
    }
#pragma unroll
    for (int ns = 0; ns < 2; ns++)
#pragma unroll
        for (int dt2 = 0; dt2 < 4; dt2++) {
            int ds_ = w * 64 + dt2 * 16 + l15;
#pragma unroll
            for (int r = 0; r < 4; r++) {
                int n = n0 + ns * 16 + quad * 4 + r;
                float val = acc[ns][dt2][r];
                if (ds_ < 128) {
                    Q[b * (NN * DD) + n * DD + ds_] = f2bf(val);
                } else {
                    int dv = ds_ - 128;
                    V[b * (NN * DD) + n * DD + dv] = f2bf(val + bv[dv]);
                }
            }
        }
}

__global__ __launch_bounds__(256) void k2_norm(
    const ushort* __restrict__ Q, ushort* __restrict__ V)
{
    const int ntile = blockIdx.x;
    const int b = blockIdx.y;
    const int n0 = ntile * 64;
    const int t = threadIdx.x;
    const int lane = t & 63, w = t >> 6, l15 = lane & 15, quad = lane >> 4;

    __shared__ __attribute__((aligned(16))) ushort Qs[64 * 136];
    __shared__ __attribute__((aligned(16))) ushort Qm[64 * 136];

    const ushort* Qb = Q + b * (NN * DD);

#pragma unroll
    for (int rep = 0; rep < 16; rep++) {
        int idx = rep * 256 + t;
        int row = idx >> 6, dp = idx & 63;
        *(uint*)&Qs[row * 136 + dp * 2] = *(const uint*)&Qb[(n0 + row) * DD + dp * 2];
    }
    __syncthreads();

    short8 afr[4];
#pragma unroll
    for (int kd = 0; kd < 4; kd++)
        afr[kd] = *(short8*)&Qs[(w * 16 + l15) * 136 + kd * 32 + quad * 8];

    float sums[4] = {0.f, 0.f, 0.f, 0.f};

    for (int m0 = 0; m0 < NN; m0 += 64) {
#pragma unroll
        for (int rep = 0; rep < 16; rep++) {
            int idx = rep * 256 + t;
            int row = idx >> 6, dp = idx & 63;
            *(uint*)&Qm[row * 136 + dp * 2] = *(const uint*)&Qb[(m0 + row) * DD + dp * 2];
        }
        __syncthreads();
#pragma unroll
        for (int ct = 0; ct < 4; ct++) {
            floatx4 s = (floatx4)(0.0f);
#pragma unroll
            for (int kd = 0; kd < 4; kd++) {
                short8 bf = *(short8*)&Qm[(ct * 16 + l15) * 136 + kd * 32 + quad * 8];
                s = __builtin_amdgcn_mfma_f32_16x16x32_bf16(afr[kd], bf, s, 0, 0, 0);
            }
#pragma unroll
            for (int r = 0; r < 4; r++)
                sums[r] += __expf(s[r] * RSCALE);
        }
        __syncthreads();
    }

#pragma unroll
    for (int r = 0; r < 4; r++) {
        float s = sums[r];
        s += __shfl_xor(s, 1);
        s += __shfl_xor(s, 2);
        s += __shfl_xor(s, 4);
        s += __shfl_xor(s, 8);
        sums[r] = s;
    }

    ushort* Vb = V + b * (NN * DD);
#pragma unroll
    for (int r = 0; r < 4; r++) {
        int n = n0 + w * 16 + quad * 4 + r;
        float inv = 1.0f / sums[r];
        short8 vv = *(short8*)&Vb[n * DD + l15 * 8];
        short8 o;
#pragma unroll
        for (int i = 0; i < 8; i++)
            o[i] = (short)f2bf(bf2f((ushort)vv[i]) * inv);
        *(short8*)&Vb[n * DD + l15 * 8] = o;
    }
}

__global__ __launch_bounds__(256) void k3_attn(
    const ushort* __restrict__ Q, const ushort* __restrict__ Vp,
    float* __restrict__ out)
{
    const int mtile = blockIdx.x;
    const int b = blockIdx.y;
    const int m0 = mtile * 64;
    const int t = threadIdx.x;
    const int lane = t & 63, w = t >> 6, l15 = lane & 15, quad = lane >> 4;

    __shared__ __attribute__((aligned(16))) ushort Qs[64 * 136];
    __shared__ __attribute__((aligned(16))) ushort Qn[32 * 136];
    __shared__ __attribute__((aligned(16))) ushort Vs[128 * 40];
    __shared__ __attribute__((aligned(16))) ushort Ps[64 * 40];

    const ushort* Qb = Q + b * (NN * DD);
    const ushort* Vpb = Vp + b * (NN * DD);

#pragma unroll
    for (int rep = 0; rep < 16; rep++) {
        int idx = rep * 256 + t;
        int row = idx >> 6, dp = idx & 63;
        *(uint*)&Qs[row * 136 + dp * 2] = *(const uint*)&Qb[(m0 + row) * DD + dp * 2];
    }
    __syncthreads();

    short8 afr[4];
#pragma unroll
    for (int kd = 0; kd < 4; kd++)
        afr[kd] = *(short8*)&Qs[(w * 16 + l15) * 136 + kd * 32 + quad * 8];

    floatx4 acc[2][4];
#pragma unroll
    for (int s = 0; s < 2; s++)
#pragma unroll
        for (int mt = 0; mt < 4; mt++) acc[s][mt] = (floatx4)(0.0f);

    for (int n0c = 0; n0c < NN; n0c += 32) {
#pragma unroll
        for (int rep = 0; rep < 8; rep++) {
            int idx = rep * 256 + t;
            int row = idx >> 6, dp = idx & 63;
            *(uint*)&Qn[row * 136 + dp * 2] = *(const uint*)&Qb[(n0c + row) * DD + dp * 2];
        }
#pragma unroll
        for (int rep = 0; rep < 8; rep++) {
            int idx = rep * 256 + t;
            int np = idx >> 7, d = idx & 127;
            uint v0 = Vpb[(n0c + np * 2) * DD + d];
            uint v1 = Vpb[(n0c + np * 2 + 1) * DD + d];
            *(uint*)&Vs[d * 40 + np * 2] = v0 | (v1 << 16);
        }
        __syncthreads();

#pragma unroll
        for (int nt2 = 0; nt2 < 2; nt2++) {
            floatx4 s = (floatx4)(0.0f);
#pragma unroll
            for (int kd = 0; kd < 4; kd++) {
                short8 bf = *(short8*)&Qn[(nt2 * 16 + l15) * 136 + kd * 32 + quad * 8];
                s = __builtin_amdgcn_mfma_f32_16x16x32_bf16(afr[kd], bf, s, 0, 0, 0);
            }
#pragma unroll
            for (int r = 0; r < 4; r++) {
                float p = __expf(s[r] * RSCALE);
                Ps[(w * 16 + quad * 4 + r) * 40 + nt2 * 16 + l15] = f2bf(p);
            }
        }
        __syncthreads();

        short8 pb[4];
#pragma unroll
        for (int mt = 0; mt < 4; mt++)
            pb[mt] = *(short8*)&Ps[(mt * 16 + l15) * 40 + quad * 8];
#pragma unroll
        for (int sub = 0; sub < 2; sub++) {
            short8 va = *(short8*)&Vs[(w * 32 + sub * 16 + l15) * 40 + quad * 8];
#pragma unroll
            for (int mt = 0; mt < 4; mt++)
                acc[sub][mt] = __builtin_amdgcn_mfma_f32_16x16x32_bf16(va, pb[mt], acc[sub][mt], 0, 0, 0);
        }
        __syncthreads();
    }

    float* ob = out + (size_t)b * DD * NN;
#pragma unroll
    for (int sub = 0; sub < 2; sub++)
#pragma unroll
        for (int mt = 0; mt < 4; mt++)
#pragma unroll
            for (int r = 0; r < 4; r++) {
                int d = w * 32 + sub * 16 + quad * 4 + r;
                int m = m0 + mt * 16 + l15;
                ob[(size_t)d * NN + m] = acc[sub][mt][r];
            }
}

extern "C" void kernel_launch(void* const* d_in, const int* in_sizes, int n_in,
                              void* d_out, int out_size, void* d_ws, size_t ws_size,
                              hipStream_t stream) {
    const float* x   = (const float*)d_in[0];
    const float* wqk = (const float*)d_in[1];
    const float* wv  = (const float*)d_in[2];
    const float* bv  = (const float*)d_in[3];
    float* out = (float*)d_out;

    // ws: Q [0,4M) | V [4M,8M) | Wbf @8M (256K) | lsum @8M+256K (64K)
    //     | VT @12M (4M) | Pg @16M (64M)   -> 80 MiB total
    ushort* Q = (ushort*)d_ws;
    ushort* V = (ushort*)((char*)d_ws + (4u << 20));

    if (ws_size >= (size_t)80 * 1024 * 1024) {
        ushort* Wbf  = (ushort*)((char*)d_ws + (8u << 20));
        float*  lsum = (float*)((char*)d_ws + (8u << 20) + (256u << 10));
        ushort* VT   = (ushort*)((char*)d_ws + (12u << 20));
        ushort* Pg   = (ushort*)((char*)d_ws + (16u << 20));

        k0_zero<<<64, 256, 0, stream>>>(lsum);
        k0_wconv<<<128, 256, 0, stream>>>(wqk, wv, Wbf);
        k1_proj<<<dim3(64, 8), 256, 0, stream>>>(x, Wbf, bv, Q, V);
        k2_qqt<<<dim3(16, 32, 8), 256, 0, stream>>>(Q, Pg, lsum);
        k2_scale_t<<<dim3(32, 8), 256, 0, stream>>>(V, lsum, VT);
        k3_gemm<<<dim3(64, 8), 256, 0, stream>>>(VT, Pg, out);
    } else {
        k1_fb<<<dim3(64, 8), 256, 0, stream>>>(x, wqk, wv, bv, Q, V);
        k2_norm<<<dim3(32, 8), 256, 0, stream>>>(Q, V);
        k3_attn<<<dim3(32, 8), 256, 0, stream>>>(Q, V, out);
    }
}